// Round 2
// baseline (435.759 us; speedup 1.0000x reference)
//
#include <hip/hip_runtime.h>
#include <hip/hip_bf16.h>
#include <cstdint>

// Problem constants
#define BB  8
#define CH  64
#define TT  4096
#define KNN 9
#define NEG_INF (-3.402823466e38f)
#define SLOTS 48          // candidate bucket per row (both halves)
#define SSTR  49          // padded LDS stride (odd -> conflict-free final scan)
#define KTH   12          // θ = 12th largest of per-half lane-union

typedef short  s16x8 __attribute__((ext_vector_type(8)));   // 8 bf16 MFMA frag
typedef float  f32x4 __attribute__((ext_vector_type(4)));   // MFMA acc

// Workspace layout (float units) — end 16,060,416 floats = 64.2 MB
constexpr size_t OFF_UB  = 0;                                  // u bf16 [B][9][T][C] ushort
constexpr size_t OFF_QTF = (size_t)BB*KNN*TT*CH/2;             //  9,437,184 qhatT f32 [B][T][C]
constexpr size_t OFF_KTF = OFF_QTF + (size_t)BB*TT*CH;         // 11,534,336 khatT f32
constexpr size_t OFF_QTB = OFF_KTF + (size_t)BB*TT*CH;         // 13,631,488 qhatT bf16 ushort
constexpr size_t OFF_KTB = OFF_QTB + (size_t)BB*TT*CH/2;       // 14,680,064 khatT bf16
constexpr size_t OFF_IDX = OFF_KTB + (size_t)BB*TT*CH/2;       // 15,728,640 idx [B][T][9]
constexpr size_t OFF_CWP = OFF_IDX + (size_t)BB*TT*KNN;        // 16,023,552 cwp [9][64][64]

__device__ __forceinline__ unsigned short f2bf(float f) {
    unsigned u = __float_as_uint(f);
    return (unsigned short)((u + 0x7FFFu + ((u >> 16) & 1u)) >> 16);
}

// value-only ascending top-4 (3 med3 + 1 max); reference params keep SROA.
__device__ __forceinline__ void insert4(float w, float (&s)[4]) {
    s[0] = __builtin_amdgcn_fmed3f(s[0], s[1], w);
    s[1] = __builtin_amdgcn_fmed3f(s[1], s[2], w);
    s[2] = __builtin_amdgcn_fmed3f(s[2], s[3], w);
    s[3] = fmaxf(s[3], w);
}

// θ = KTH-th largest of the union of the quad's 16 top-4 lists (destroys
// lists). Union ⊆ half-row ⇒ θ ≤ half-row's KTH-th largest (safe threshold).
__device__ __forceinline__ float popTheta4(float (&s)[4], int lane) {
    float theta = NEG_INF;
    #pragma unroll 1
    for (int p = 0; p < KTH; ++p) {
        float h = s[3];
        float m = h;
        m = fmaxf(m, __shfl_xor(m, 1));
        m = fmaxf(m, __shfl_xor(m, 2));
        m = fmaxf(m, __shfl_xor(m, 4));
        m = fmaxf(m, __shfl_xor(m, 8));
        unsigned long long bal = __ballot(h == m);
        unsigned qb = (unsigned)((bal >> (lane & 48)) & 0xFFFFull);
        int owner = __ffs(qb) - 1;
        if ((lane & 15) == owner) {
            s[3] = s[2]; s[2] = s[1]; s[1] = s[0]; s[0] = NEG_INF;
        }
        theta = m;
    }
    return theta;
}

// exact sorted-9 insert, value desc w/ index-asc tiebreak (final sort only)
__device__ __forceinline__ void insert9x(float w, int wi, float (&s)[9], int (&si)[9]) {
    bool c[9];
    #pragma unroll
    for (int k = 0; k < 9; ++k) c[k] = (w > s[k]) || (w == s[k] && wi < si[k]);
    #pragma unroll
    for (int k = 0; k < 8; ++k) si[k] = c[k + 1] ? si[k + 1] : (c[k] ? wi : si[k]);
    si[8] = c[8] ? wi : si[8];
    #pragma unroll
    for (int k = 0; k < 8; ++k) s[k] = c[k + 1] ? s[k + 1] : (c[k] ? w : s[k]);
    s[8] = c[8] ? w : s[8];
}

// ---------------------------------------------------------------------------
// K0: repack conv_w[o][cc*9+kk] -> cwp[kk][cc][o]
// ---------------------------------------------------------------------------
__global__ void repack_cw_kernel(const float* __restrict__ cw, float* __restrict__ cwp) {
    int e = blockIdx.x * blockDim.x + threadIdx.x;
    if (e >= KNN * CH * CH) return;
    int o  = e & 63;
    int cc = (e >> 6) & 63;
    int kk = e >> 12;
    cwp[e] = cw[o * (CH * KNN) + cc * KNN + kk];
}

// ---------------------------------------------------------------------------
// K1: QKV + L2 normalize + u-projection (u bf16) + q/k T-layout fp32 & bf16
// ---------------------------------------------------------------------------
__global__ __launch_bounds__(256) void qkvu_kernel(
        const float* __restrict__ x,
        const float* __restrict__ Wq, const float* __restrict__ Wk, const float* __restrict__ Wv,
        const float* __restrict__ cwp,
        float* __restrict__ qtf, float* __restrict__ ktf,
        unsigned short* __restrict__ qtb, unsigned short* __restrict__ ktb,
        unsigned short* __restrict__ ub) {
    __shared__ __align__(16) float xs[CH * 64];
    __shared__ __align__(16) float vs[CH * 64];
    __shared__ __align__(16) float wl[CH * 64];
    __shared__ float pq[4 * 64], pk[4 * 64];

    const int b   = blockIdx.x >> 6;
    const int tb  = blockIdx.x & 63;
    const int tid = threadIdx.x;

    const float* xb = x + ((size_t)b * CH) * TT + tb * 64;
    #pragma unroll
    for (int m = 0; m < 16; ++m) {
        int l = tid + 256 * m;
        xs[l] = xb[(size_t)(l >> 6) * TT + (l & 63)];
    }
    __syncthreads();

    const int t = tid & 63;
    const int g = __builtin_amdgcn_readfirstlane(tid >> 6);
    const int d0 = g * 16;

    float qa[16], ka[16], va[16];
    #pragma unroll
    for (int dd = 0; dd < 16; ++dd) { qa[dd] = 0.f; ka[dd] = 0.f; va[dd] = 0.f; }

    #pragma unroll 4
    for (int c = 0; c < CH; ++c) {
        float xv = xs[c * 64 + t];
        #pragma unroll
        for (int dd = 0; dd < 16; ++dd) {
            qa[dd] = fmaf(Wq[(d0 + dd) * CH + c], xv, qa[dd]);
            ka[dd] = fmaf(Wk[(d0 + dd) * CH + c], xv, ka[dd]);
            va[dd] = fmaf(Wv[(d0 + dd) * CH + c], xv, va[dd]);
        }
    }

    float sq = 0.f, sk = 0.f;
    #pragma unroll
    for (int dd = 0; dd < 16; ++dd) { sq = fmaf(qa[dd], qa[dd], sq); sk = fmaf(ka[dd], ka[dd], sk); }
    pq[g * 64 + t] = sq;
    pk[g * 64 + t] = sk;
    __syncthreads();

    const float nq = sqrtf(pq[t] + pq[64 + t] + pq[128 + t] + pq[192 + t]);
    const float nk = sqrtf(pk[t] + pk[64 + t] + pk[128 + t] + pk[192 + t]);
    const float isq = 1.0f / fmaxf(nq, 1e-12f);
    const float isk = 1.0f / fmaxf(nk, 1e-12f);

    const size_t tg = (size_t)tb * 64 + t;
    float qn[16], kn[16];
    #pragma unroll
    for (int dd = 0; dd < 16; ++dd) {
        qn[dd] = qa[dd] * isq;
        kn[dd] = ka[dd] * isk;
        vs[(d0 + dd) * 64 + t] = va[dd];
    }
    float* qf = qtf + ((size_t)b * TT + tg) * CH + d0;
    float* kf = ktf + ((size_t)b * TT + tg) * CH + d0;
    #pragma unroll
    for (int p = 0; p < 4; ++p) {
        *(float4*)&qf[p * 4] = make_float4(qn[p*4], qn[p*4+1], qn[p*4+2], qn[p*4+3]);
        *(float4*)&kf[p * 4] = make_float4(kn[p*4], kn[p*4+1], kn[p*4+2], kn[p*4+3]);
    }
    unsigned* qh = (unsigned*)(qtb + ((size_t)b * TT + tg) * CH + d0);
    unsigned* kh = (unsigned*)(ktb + ((size_t)b * TT + tg) * CH + d0);
    #pragma unroll
    for (int p = 0; p < 8; ++p) {
        qh[p] = (unsigned)f2bf(qn[2*p]) | ((unsigned)f2bf(qn[2*p+1]) << 16);
        kh[p] = (unsigned)f2bf(kn[2*p]) | ((unsigned)f2bf(kn[2*p+1]) << 16);
    }
    __syncthreads();

    const int to = tid & 15;
    const int tt = tid >> 4;
    for (int kk = 0; kk < KNN; ++kk) {
        #pragma unroll
        for (int m = 0; m < 16; ++m) {
            int l = tid + 256 * m;
            wl[l] = cwp[kk * (CH * CH) + l];
        }
        __syncthreads();
        float acc[4][4];
        #pragma unroll
        for (int i = 0; i < 4; ++i)
            #pragma unroll
            for (int j = 0; j < 4; ++j) acc[i][j] = 0.f;

        #pragma unroll 8
        for (int cc = 0; cc < CH; ++cc) {
            float4 wv = *(const float4*)&wl[cc * 64 + 4 * to];
            float4 vv = *(const float4*)&vs[cc * 64 + 4 * tt];
            const float wj[4] = {wv.x, wv.y, wv.z, wv.w};
            const float vi[4] = {vv.x, vv.y, vv.z, vv.w};
            #pragma unroll
            for (int i = 0; i < 4; ++i)
                #pragma unroll
                for (int j = 0; j < 4; ++j) acc[i][j] = fmaf(vi[i], wj[j], acc[i][j]);
        }
        #pragma unroll
        for (int i = 0; i < 4; ++i) {
            size_t row = (size_t)(b * KNN + kk) * TT + tb * 64 + 4 * tt + i;
            unsigned w0 = (unsigned)f2bf(acc[i][0]) | ((unsigned)f2bf(acc[i][1]) << 16);
            unsigned w1 = (unsigned)f2bf(acc[i][2]) | ((unsigned)f2bf(acc[i][3]) << 16);
            *(uint2*)&ub[row * CH + 4 * to] = make_uint2(w0, w1);
        }
        __syncthreads();
    }
}

// ---------------------------------------------------------------------------
// K2: BARRIER-FREE bf16-MFMA sim + top-4 prefilter + θ-collect + exact rescore
//     grid 1024 = b(8, XCD swizzle: batch's q/k bf16 L2-resident) x ib(128).
//     Each block: 32 k-rows x all 4096 q cols. block 256 = 4 waves, 2x2:
//     wave (w2r,w2c) owns rows [w2r*16,+16) x cols [w2c*2048,+2048).
//     vs round-0: rows per block halved -> 4 blocks/CU -> 16 waves/CU
//     (4/SIMD, 2x TLP) with SMALLER per-wave register state (ka[2], acc[8]).
//     Same per-half θ statistics, SLOTS unchanged; LDS stride padded to 49.
// ---------------------------------------------------------------------------
__global__ __launch_bounds__(256, 4) void sim_topk_kernel(
        const unsigned short* __restrict__ qtb, const unsigned short* __restrict__ ktb,
        const float* __restrict__ qtf, const float* __restrict__ ktf,
        int* __restrict__ idxout) {
    __shared__ int   cnt[32];
    __shared__ int   bkt[32 * SSTR];
    __shared__ float wbf[32 * SSTR];

    const int b    = blockIdx.x & 7;
    const int ib   = blockIdx.x >> 3;      // 0..127 (32-row tile)
    const int tid  = threadIdx.x;
    const int lane = tid & 63;
    const int w    = tid >> 6;             // wave 0..3
    const int w2r  = w >> 1;               // row tile (16 rows)
    const int w2c  = w & 1;                // col half
    const int quad = lane >> 4;
    const int l15  = lane & 15;

    if (tid < 32) cnt[tid] = 0;
    __syncthreads();

    // k A-fragment in registers: row = w2r*16 + l15, ch = quad*8 + ks*32
    const unsigned short* kb = ktb + ((size_t)b * TT + ib * 32 + w2r * 16) * CH;
    s16x8 ka[2];
    #pragma unroll
    for (int ks = 0; ks < 2; ++ks)
        ka[ks] = *(const s16x8*)(kb + (size_t)l15 * CH + ks * 32 + quad * 8);

    const unsigned short* qbB = qtb + ((size_t)b * TT + w2c * 2048) * CH;

    float s[4][4];
    #pragma unroll
    for (int rg = 0; rg < 4; ++rg)
        #pragma unroll
        for (int k = 0; k < 4; ++k) s[rg][k] = NEG_INF;

    // ------------------ PASS A: values-only top-4 (no barriers) ------------
    for (int jt = 0; jt < 16; ++jt) {
        const unsigned short* qrow = qbB + (size_t)(jt * 128 + l15) * CH + quad * 8;
        s16x8 qf[8][2];
        #pragma unroll
        for (int jj = 0; jj < 8; ++jj)
            #pragma unroll
            for (int ks = 0; ks < 2; ++ks)
                qf[jj][ks] = *(const s16x8*)(qrow + (size_t)jj * 16 * CH + ks * 32);

        f32x4 acc[8];
        #pragma unroll
        for (int jj = 0; jj < 8; ++jj) acc[jj] = (f32x4){0.f, 0.f, 0.f, 0.f};
        #pragma unroll
        for (int ks = 0; ks < 2; ++ks)
            #pragma unroll
            for (int jj = 0; jj < 8; ++jj)
                acc[jj] = __builtin_amdgcn_mfma_f32_16x16x32_bf16(ka[ks], qf[jj][ks], acc[jj], 0, 0, 0);

        #pragma unroll
        for (int jj = 0; jj < 8; ++jj) {
            insert4(acc[jj][0], s[0]);
            insert4(acc[jj][1], s[1]);
            insert4(acc[jj][2], s[2]);
            insert4(acc[jj][3], s[3]);
        }
    }

    // per-(row,half) θ — valid per half; no cross-wave merge needed
    float th[4];
    #pragma unroll
    for (int rg = 0; rg < 4; ++rg) th[rg] = popTheta4(s[rg], lane);

    // ------------------ PASS B: recompute (bitwise-identical) + collect ----
    for (int jt = 0; jt < 16; ++jt) {
        const unsigned short* qrow = qbB + (size_t)(jt * 128 + l15) * CH + quad * 8;
        s16x8 qf[8][2];
        #pragma unroll
        for (int jj = 0; jj < 8; ++jj)
            #pragma unroll
            for (int ks = 0; ks < 2; ++ks)
                qf[jj][ks] = *(const s16x8*)(qrow + (size_t)jj * 16 * CH + ks * 32);

        f32x4 acc[8];
        #pragma unroll
        for (int jj = 0; jj < 8; ++jj) acc[jj] = (f32x4){0.f, 0.f, 0.f, 0.f};
        #pragma unroll
        for (int ks = 0; ks < 2; ++ks)
            #pragma unroll
            for (int jj = 0; jj < 8; ++jj)
                acc[jj] = __builtin_amdgcn_mfma_f32_16x16x32_bf16(ka[ks], qf[jj][ks], acc[jj], 0, 0, 0);

        #pragma unroll
        for (int jj = 0; jj < 8; ++jj) {
            const int j = w2c * 2048 + jt * 128 + jj * 16 + l15;
            #pragma unroll
            for (int rg = 0; rg < 4; ++rg) {
                if (acc[jj][rg] >= th[rg]) {
                    int rowl = w2r * 16 + quad * 4 + rg;        // 0..31
                    int sl = atomicAdd(&cnt[rowl], 1);
                    if (sl < SLOTS) bkt[rowl * SSTR + sl] = j;
                }
            }
        }
    }
    __syncthreads();

    // ------------------ exact fp32 rescore (L2-hot q/k fp32) ---------------
    {
        int r = tid >> 3, sub = tid & 7;
        int n = min(cnt[r], SLOTS);
        const float* krow = ktf + ((size_t)b * TT + ib * 32 + r) * CH;
        for (int m = sub; m < n; m += 8) {
            int j = bkt[r * SSTR + m];
            const float* qrow = qtf + ((size_t)b * TT + j) * CH;
            float wv = 0.f;
            #pragma unroll
            for (int c4 = 0; c4 < 16; ++c4) {
                float4 kv = *(const float4*)&krow[c4 * 4];
                float4 qv = *(const float4*)&qrow[c4 * 4];
                wv = fmaf(kv.x, qv.x, wv); wv = fmaf(kv.y, qv.y, wv);
                wv = fmaf(kv.z, qv.z, wv); wv = fmaf(kv.w, qv.w, wv);
            }
            wbf[r * SSTR + m] = wv;
        }
    }
    __syncthreads();

    if (tid < 32) {
        int n = min(cnt[tid], SLOTS);
        float s9[9]; int si9[9];
        #pragma unroll
        for (int k = 0; k < 9; ++k) { s9[k] = NEG_INF; si9[k] = 0x7fffffff; }
        #pragma unroll 1
        for (int m = 0; m < n; ++m) insert9x(wbf[tid * SSTR + m], bkt[tid * SSTR + m], s9, si9);
        int* orow = idxout + ((size_t)b * TT + ib * 32 + tid) * KNN;
        #pragma unroll
        for (int m = 0; m < 9; ++m) orow[m] = si9[8 - m];
    }
}

// ---------------------------------------------------------------------------
// K3: out[b][o][t] = conv_b[o] + sum_kk u_bf16[b][kk][idx[t][kk]][o]
// ---------------------------------------------------------------------------
__global__ __launch_bounds__(256) void gather_conv_kernel(
        const unsigned short* __restrict__ ub, const int* __restrict__ idxin,
        const float* __restrict__ conv_b, float* __restrict__ out) {
    __shared__ int   sidx[64 * KNN];
    __shared__ float cb[CH];
    const int b   = blockIdx.x & 7;
    const int tb  = blockIdx.x >> 3;
    const int tid = threadIdx.x;

    if (tid < CH) cb[tid] = conv_b[tid];
    const int* ig = idxin + ((size_t)b * TT + tb * 64) * KNN;
    for (int l = tid; l < 64 * KNN; l += 256) sidx[l] = ig[l];
    __syncthreads();

    const int tl = tid & 63;
    const int og = tid >> 6;
    const int o0 = og * 16;

    float acc[16];
    #pragma unroll
    for (int q = 0; q < 16; ++q) acc[q] = cb[o0 + q];

    #pragma unroll
    for (int kk = 0; kk < KNN; ++kk) {
        int j = sidx[tl * KNN + kk];
        const unsigned short* up = ub + (((size_t)(b * KNN + kk)) * TT + j) * CH + o0;
        #pragma unroll
        for (int q8 = 0; q8 < 2; ++q8) {
            uint4 raw = *(const uint4*)&up[q8 * 8];
            unsigned rw[4] = {raw.x, raw.y, raw.z, raw.w};
            #pragma unroll
            for (int p = 0; p < 4; ++p) {
                acc[q8 * 8 + 2 * p]     += __uint_as_float(rw[p] << 16);
                acc[q8 * 8 + 2 * p + 1] += __uint_as_float(rw[p] & 0xFFFF0000u);
            }
        }
    }
    const int t = tb * 64 + tl;
    #pragma unroll
    for (int q = 0; q < 16; ++q)
        out[((size_t)b * CH + o0 + q) * TT + t] = acc[q];
}

// ---------------------------------------------------------------------------
extern "C" void kernel_launch(void* const* d_in, const int* in_sizes, int n_in,
                              void* d_out, int out_size, void* d_ws, size_t ws_size,
                              hipStream_t stream) {
    const float* x   = (const float*)d_in[0];
    const float* Wq  = (const float*)d_in[1];
    const float* Wk  = (const float*)d_in[2];
    const float* Wv  = (const float*)d_in[3];
    const float* cw  = (const float*)d_in[4];
    const float* cbp = (const float*)d_in[5];

    float* ws = (float*)d_ws;
    unsigned short* ub  = (unsigned short*)(ws + OFF_UB);
    float* qtf          = ws + OFF_QTF;
    float* ktf          = ws + OFF_KTF;
    unsigned short* qtb = (unsigned short*)(ws + OFF_QTB);
    unsigned short* ktb = (unsigned short*)(ws + OFF_KTB);
    int*   idx          = (int*)(ws + OFF_IDX);
    float* cwp          = ws + OFF_CWP;
    float* out          = (float*)d_out;

    repack_cw_kernel<<<(KNN * CH * CH + 255) / 256, 256, 0, stream>>>(cw, cwp);
    qkvu_kernel<<<BB * 64, 256, 0, stream>>>(x, Wq, Wk, Wv, cwp, qtf, ktf, qtb, ktb, ub);
    sim_topk_kernel<<<BB * 128, 256, 0, stream>>>(qtb, ktb, qtf, ktf, idx);
    gather_conv_kernel<<<BB * 64, 256, 0, stream>>>(ub, idx, cbp, out);
}

// Round 3
// 338.184 us; speedup vs baseline: 1.2885x; 1.2885x over previous
//
#include <hip/hip_runtime.h>
#include <hip/hip_bf16.h>
#include <cstdint>

// Problem constants
#define BB  8
#define CH  64
#define TT  4096
#define KNN 9
#define NEG_INF (-3.402823466e38f)
#define SLOTS 80          // candidate bucket per row (4 col-strips x ~11-13)
#define SSTR  81          // padded LDS stride (odd -> conflict-free scans)
#define KTH   10          // θ = 10th largest of per-strip lane-union (>=9 exact)

typedef short  s16x8 __attribute__((ext_vector_type(8)));   // 8 bf16 MFMA frag
typedef float  f32x4 __attribute__((ext_vector_type(4)));   // MFMA acc

// Workspace layout (float units) — end 16,060,416 floats = 64.2 MB
constexpr size_t OFF_UB  = 0;                                  // u bf16 [B][9][T][C] ushort
constexpr size_t OFF_QTF = (size_t)BB*KNN*TT*CH/2;             //  9,437,184 qhatT f32 [B][T][C]
constexpr size_t OFF_KTF = OFF_QTF + (size_t)BB*TT*CH;         // 11,534,336 khatT f32
constexpr size_t OFF_QTB = OFF_KTF + (size_t)BB*TT*CH;         // 13,631,488 qhatT bf16 ushort
constexpr size_t OFF_KTB = OFF_QTB + (size_t)BB*TT*CH/2;       // 14,680,064 khatT bf16
constexpr size_t OFF_IDX = OFF_KTB + (size_t)BB*TT*CH/2;       // 15,728,640 idx [B][T][9]
constexpr size_t OFF_CWP = OFF_IDX + (size_t)BB*TT*KNN;        // 16,023,552 cwp [9][64][64]

__device__ __forceinline__ unsigned short f2bf(float f) {
    unsigned u = __float_as_uint(f);
    return (unsigned short)((u + 0x7FFFu + ((u >> 16) & 1u)) >> 16);
}

// value-only ascending top-4 (3 med3 + 1 max); reference params keep SROA.
__device__ __forceinline__ void insert4(float w, float (&s)[4]) {
    s[0] = __builtin_amdgcn_fmed3f(s[0], s[1], w);
    s[1] = __builtin_amdgcn_fmed3f(s[1], s[2], w);
    s[2] = __builtin_amdgcn_fmed3f(s[2], s[3], w);
    s[3] = fmaxf(s[3], w);
}

// θ = KTH-th largest of the union of the quad's 16 top-4 lists (destroys
// lists). Union ⊆ strip-row values ⇒ θ = union's KTH-th ≤ strip's KTH-th
// ≤ strip's 9th. Any row-global top-9 element lying in this strip is within
// the strip's top-9 (strip ⊆ row), hence ≥ θ ⇒ collected. Exact.
__device__ __forceinline__ float popTheta4(float (&s)[4], int lane) {
    float theta = NEG_INF;
    #pragma unroll 1
    for (int p = 0; p < KTH; ++p) {
        float h = s[3];
        float m = h;
        m = fmaxf(m, __shfl_xor(m, 1));
        m = fmaxf(m, __shfl_xor(m, 2));
        m = fmaxf(m, __shfl_xor(m, 4));
        m = fmaxf(m, __shfl_xor(m, 8));
        unsigned long long bal = __ballot(h == m);
        unsigned qb = (unsigned)((bal >> (lane & 48)) & 0xFFFFull);
        int owner = __ffs(qb) - 1;
        if ((lane & 15) == owner) {
            s[3] = s[2]; s[2] = s[1]; s[1] = s[0]; s[0] = NEG_INF;
        }
        theta = m;
    }
    return theta;
}

// exact sorted-9 insert, value desc w/ index-asc tiebreak (final sort only)
__device__ __forceinline__ void insert9x(float w, int wi, float (&s)[9], int (&si)[9]) {
    bool c[9];
    #pragma unroll
    for (int k = 0; k < 9; ++k) c[k] = (w > s[k]) || (w == s[k] && wi < si[k]);
    #pragma unroll
    for (int k = 0; k < 8; ++k) si[k] = c[k + 1] ? si[k + 1] : (c[k] ? wi : si[k]);
    si[8] = c[8] ? wi : si[8];
    #pragma unroll
    for (int k = 0; k < 8; ++k) s[k] = c[k + 1] ? s[k + 1] : (c[k] ? w : s[k]);
    s[8] = c[8] ? w : s[8];
}

// ---------------------------------------------------------------------------
// K0: repack conv_w[o][cc*9+kk] -> cwp[kk][cc][o]
// ---------------------------------------------------------------------------
__global__ void repack_cw_kernel(const float* __restrict__ cw, float* __restrict__ cwp) {
    int e = blockIdx.x * blockDim.x + threadIdx.x;
    if (e >= KNN * CH * CH) return;
    int o  = e & 63;
    int cc = (e >> 6) & 63;
    int kk = e >> 12;
    cwp[e] = cw[o * (CH * KNN) + cc * KNN + kk];
}

// ---------------------------------------------------------------------------
// K1: QKV + L2 normalize + u-projection (u bf16) + q/k T-layout fp32 & bf16
// ---------------------------------------------------------------------------
__global__ __launch_bounds__(256) void qkvu_kernel(
        const float* __restrict__ x,
        const float* __restrict__ Wq, const float* __restrict__ Wk, const float* __restrict__ Wv,
        const float* __restrict__ cwp,
        float* __restrict__ qtf, float* __restrict__ ktf,
        unsigned short* __restrict__ qtb, unsigned short* __restrict__ ktb,
        unsigned short* __restrict__ ub) {
    __shared__ __align__(16) float xs[CH * 64];
    __shared__ __align__(16) float vs[CH * 64];
    __shared__ __align__(16) float wl[CH * 64];
    __shared__ float pq[4 * 64], pk[4 * 64];

    const int b   = blockIdx.x >> 6;
    const int tb  = blockIdx.x & 63;
    const int tid = threadIdx.x;

    const float* xb = x + ((size_t)b * CH) * TT + tb * 64;
    #pragma unroll
    for (int m = 0; m < 16; ++m) {
        int l = tid + 256 * m;
        xs[l] = xb[(size_t)(l >> 6) * TT + (l & 63)];
    }
    __syncthreads();

    const int t = tid & 63;
    const int g = __builtin_amdgcn_readfirstlane(tid >> 6);
    const int d0 = g * 16;

    float qa[16], ka[16], va[16];
    #pragma unroll
    for (int dd = 0; dd < 16; ++dd) { qa[dd] = 0.f; ka[dd] = 0.f; va[dd] = 0.f; }

    #pragma unroll 4
    for (int c = 0; c < CH; ++c) {
        float xv = xs[c * 64 + t];
        #pragma unroll
        for (int dd = 0; dd < 16; ++dd) {
            qa[dd] = fmaf(Wq[(d0 + dd) * CH + c], xv, qa[dd]);
            ka[dd] = fmaf(Wk[(d0 + dd) * CH + c], xv, ka[dd]);
            va[dd] = fmaf(Wv[(d0 + dd) * CH + c], xv, va[dd]);
        }
    }

    float sq = 0.f, sk = 0.f;
    #pragma unroll
    for (int dd = 0; dd < 16; ++dd) { sq = fmaf(qa[dd], qa[dd], sq); sk = fmaf(ka[dd], ka[dd], sk); }
    pq[g * 64 + t] = sq;
    pk[g * 64 + t] = sk;
    __syncthreads();

    const float nq = sqrtf(pq[t] + pq[64 + t] + pq[128 + t] + pq[192 + t]);
    const float nk = sqrtf(pk[t] + pk[64 + t] + pk[128 + t] + pk[192 + t]);
    const float isq = 1.0f / fmaxf(nq, 1e-12f);
    const float isk = 1.0f / fmaxf(nk, 1e-12f);

    const size_t tg = (size_t)tb * 64 + t;
    float qn[16], kn[16];
    #pragma unroll
    for (int dd = 0; dd < 16; ++dd) {
        qn[dd] = qa[dd] * isq;
        kn[dd] = ka[dd] * isk;
        vs[(d0 + dd) * 64 + t] = va[dd];
    }
    float* qf = qtf + ((size_t)b * TT + tg) * CH + d0;
    float* kf = ktf + ((size_t)b * TT + tg) * CH + d0;
    #pragma unroll
    for (int p = 0; p < 4; ++p) {
        *(float4*)&qf[p * 4] = make_float4(qn[p*4], qn[p*4+1], qn[p*4+2], qn[p*4+3]);
        *(float4*)&kf[p * 4] = make_float4(kn[p*4], kn[p*4+1], kn[p*4+2], kn[p*4+3]);
    }
    unsigned* qh = (unsigned*)(qtb + ((size_t)b * TT + tg) * CH + d0);
    unsigned* kh = (unsigned*)(ktb + ((size_t)b * TT + tg) * CH + d0);
    #pragma unroll
    for (int p = 0; p < 8; ++p) {
        qh[p] = (unsigned)f2bf(qn[2*p]) | ((unsigned)f2bf(qn[2*p+1]) << 16);
        kh[p] = (unsigned)f2bf(kn[2*p]) | ((unsigned)f2bf(kn[2*p+1]) << 16);
    }
    __syncthreads();

    const int to = tid & 15;
    const int tt = tid >> 4;
    for (int kk = 0; kk < KNN; ++kk) {
        #pragma unroll
        for (int m = 0; m < 16; ++m) {
            int l = tid + 256 * m;
            wl[l] = cwp[kk * (CH * CH) + l];
        }
        __syncthreads();
        float acc[4][4];
        #pragma unroll
        for (int i = 0; i < 4; ++i)
            #pragma unroll
            for (int j = 0; j < 4; ++j) acc[i][j] = 0.f;

        #pragma unroll 8
        for (int cc = 0; cc < CH; ++cc) {
            float4 wv = *(const float4*)&wl[cc * 64 + 4 * to];
            float4 vv = *(const float4*)&vs[cc * 64 + 4 * tt];
            const float wj[4] = {wv.x, wv.y, wv.z, wv.w};
            const float vi[4] = {vv.x, vv.y, vv.z, vv.w};
            #pragma unroll
            for (int i = 0; i < 4; ++i)
                #pragma unroll
                for (int j = 0; j < 4; ++j) acc[i][j] = fmaf(vi[i], wj[j], acc[i][j]);
        }
        #pragma unroll
        for (int i = 0; i < 4; ++i) {
            size_t row = (size_t)(b * KNN + kk) * TT + tb * 64 + 4 * tt + i;
            unsigned w0 = (unsigned)f2bf(acc[i][0]) | ((unsigned)f2bf(acc[i][1]) << 16);
            unsigned w1 = (unsigned)f2bf(acc[i][2]) | ((unsigned)f2bf(acc[i][3]) << 16);
            *(uint2*)&ub[row * CH + 4 * to] = make_uint2(w0, w1);
        }
        __syncthreads();
    }
}

// ---------------------------------------------------------------------------
// K2: BARRIER-FREE bf16-MFMA sim + top-4 prefilter + θ-collect + exact rescore
//     grid 512 = b(8, XCD swizzle: batch's q/k bf16 L2-resident) x ib(64).
//     Block: 64 k-rows x 4096 q-cols. 4 waves; wave w owns ALL 64 rows
//     (ka[4][2] in regs) x a 1024-col strip [w*1024,+1024). Each q line is
//     read ONCE per block per pass (vs 2x in the 2x2 tiling) -> halves the
//     dominant L1 line traffic. NO manual double-buffer (r1 lesson: compiler
//     schedules better); small per-step state: qf[4][2] (32 VGPR), acc[4]
//     (16 VGPR, rt-outer loop). θ per (row,strip) from quad-union top-4,
//     KTH=10 (θ ≤ strip 9th -> exact). SLOTS 80, odd stride 81.
// ---------------------------------------------------------------------------
__global__ __launch_bounds__(256, 2) void sim_topk_kernel(
        const unsigned short* __restrict__ qtb, const unsigned short* __restrict__ ktb,
        const float* __restrict__ qtf, const float* __restrict__ ktf,
        int* __restrict__ idxout) {
    __shared__ int   cnt[64];
    __shared__ int   bkt[64 * SSTR];
    __shared__ float wbf[64 * SSTR];

    const int b    = blockIdx.x & 7;
    const int ib   = blockIdx.x >> 3;      // 0..63
    const int tid  = threadIdx.x;
    const int lane = tid & 63;
    const int w    = __builtin_amdgcn_readfirstlane(tid >> 6);  // wave -> col strip
    const int quad = lane >> 4;
    const int l15  = lane & 15;

    if (tid < 64) cnt[tid] = 0;
    __syncthreads();

    // k A-fragments: ALL 64 rows. row = rt*16 + l15, k-chunk = quad*8 + ks*32
    const unsigned short* kb = ktb + ((size_t)b * TT + ib * 64) * CH;
    s16x8 ka[4][2];
    #pragma unroll
    for (int rt = 0; rt < 4; ++rt)
        #pragma unroll
        for (int ks = 0; ks < 2; ++ks)
            ka[rt][ks] = *(const s16x8*)(kb + (size_t)(rt * 16 + l15) * CH + ks * 32 + quad * 8);

    const unsigned short* qbB = qtb + ((size_t)b * TT + w * 1024) * CH;

    // per-(rt,rg) ascending top-4 lists over this wave's strip
    float s[4][4][4];
    #pragma unroll
    for (int rt = 0; rt < 4; ++rt)
        #pragma unroll
        for (int rg = 0; rg < 4; ++rg)
            #pragma unroll
            for (int k = 0; k < 4; ++k) s[rt][rg][k] = NEG_INF;

    // ------------------ PASS A: values-only top-4 (no barriers) ------------
    for (int it = 0; it < 16; ++it) {
        const unsigned short* qrow = qbB + (size_t)(it * 64 + l15) * CH + quad * 8;
        s16x8 qf[4][2];
        #pragma unroll
        for (int jj = 0; jj < 4; ++jj)
            #pragma unroll
            for (int ks = 0; ks < 2; ++ks)
                qf[jj][ks] = *(const s16x8*)(qrow + (size_t)jj * 16 * CH + ks * 32);

        #pragma unroll
        for (int rt = 0; rt < 4; ++rt) {
            f32x4 acc[4];
            #pragma unroll
            for (int jj = 0; jj < 4; ++jj) acc[jj] = (f32x4){0.f, 0.f, 0.f, 0.f};
            #pragma unroll
            for (int ks = 0; ks < 2; ++ks)
                #pragma unroll
                for (int jj = 0; jj < 4; ++jj)
                    acc[jj] = __builtin_amdgcn_mfma_f32_16x16x32_bf16(ka[rt][ks], qf[jj][ks], acc[jj], 0, 0, 0);
            #pragma unroll
            for (int jj = 0; jj < 4; ++jj) {
                insert4(acc[jj][0], s[rt][0]);
                insert4(acc[jj][1], s[rt][1]);
                insert4(acc[jj][2], s[rt][2]);
                insert4(acc[jj][3], s[rt][3]);
            }
        }
    }

    // per-(row, strip) θ — valid per strip; no cross-wave merge needed
    float th[4][4];
    #pragma unroll
    for (int rt = 0; rt < 4; ++rt)
        #pragma unroll
        for (int rg = 0; rg < 4; ++rg)
            th[rt][rg] = popTheta4(s[rt][rg], lane);

    // ------------------ PASS B: recompute (bitwise-identical) + collect ----
    for (int it = 0; it < 16; ++it) {
        const unsigned short* qrow = qbB + (size_t)(it * 64 + l15) * CH + quad * 8;
        s16x8 qf[4][2];
        #pragma unroll
        for (int jj = 0; jj < 4; ++jj)
            #pragma unroll
            for (int ks = 0; ks < 2; ++ks)
                qf[jj][ks] = *(const s16x8*)(qrow + (size_t)jj * 16 * CH + ks * 32);

        #pragma unroll
        for (int rt = 0; rt < 4; ++rt) {
            f32x4 acc[4];
            #pragma unroll
            for (int jj = 0; jj < 4; ++jj) acc[jj] = (f32x4){0.f, 0.f, 0.f, 0.f};
            #pragma unroll
            for (int ks = 0; ks < 2; ++ks)
                #pragma unroll
                for (int jj = 0; jj < 4; ++jj)
                    acc[jj] = __builtin_amdgcn_mfma_f32_16x16x32_bf16(ka[rt][ks], qf[jj][ks], acc[jj], 0, 0, 0);
            #pragma unroll
            for (int jj = 0; jj < 4; ++jj) {
                const int j = w * 1024 + it * 64 + jj * 16 + l15;
                #pragma unroll
                for (int rg = 0; rg < 4; ++rg) {
                    if (acc[jj][rg] >= th[rt][rg]) {
                        int rowl = rt * 16 + quad * 4 + rg;     // 0..63
                        int sl = atomicAdd(&cnt[rowl], 1);
                        if (sl < SLOTS) bkt[rowl * SSTR + sl] = j;
                    }
                }
            }
        }
    }
    __syncthreads();

    // ------------------ exact fp32 rescore (L2-hot q/k fp32) ---------------
    {
        int r = tid >> 2, sub = tid & 3;
        int n = min(cnt[r], SLOTS);
        const float* krow = ktf + ((size_t)b * TT + ib * 64 + r) * CH;
        for (int m = sub; m < n; m += 4) {
            int j = bkt[r * SSTR + m];
            const float* qrow = qtf + ((size_t)b * TT + j) * CH;
            float wv = 0.f;
            #pragma unroll
            for (int c4 = 0; c4 < 16; ++c4) {
                float4 kv = *(const float4*)&krow[c4 * 4];
                float4 qv = *(const float4*)&qrow[c4 * 4];
                wv = fmaf(kv.x, qv.x, wv); wv = fmaf(kv.y, qv.y, wv);
                wv = fmaf(kv.z, qv.z, wv); wv = fmaf(kv.w, qv.w, wv);
            }
            wbf[r * SSTR + m] = wv;
        }
    }
    __syncthreads();

    if (tid < 64) {
        int n = min(cnt[tid], SLOTS);
        float s9[9]; int si9[9];
        #pragma unroll
        for (int k = 0; k < 9; ++k) { s9[k] = NEG_INF; si9[k] = 0x7fffffff; }
        #pragma unroll 1
        for (int m = 0; m < n; ++m) insert9x(wbf[tid * SSTR + m], bkt[tid * SSTR + m], s9, si9);
        int* orow = idxout + ((size_t)b * TT + ib * 64 + tid) * KNN;
        #pragma unroll
        for (int m = 0; m < 9; ++m) orow[m] = si9[8 - m];
    }
}

// ---------------------------------------------------------------------------
// K3: out[b][o][t] = conv_b[o] + sum_kk u_bf16[b][kk][idx[t][kk]][o]
// ---------------------------------------------------------------------------
__global__ __launch_bounds__(256) void gather_conv_kernel(
        const unsigned short* __restrict__ ub, const int* __restrict__ idxin,
        const float* __restrict__ conv_b, float* __restrict__ out) {
    __shared__ int   sidx[64 * KNN];
    __shared__ float cb[CH];
    const int b   = blockIdx.x & 7;
    const int tb  = blockIdx.x >> 3;
    const int tid = threadIdx.x;

    if (tid < CH) cb[tid] = conv_b[tid];
    const int* ig = idxin + ((size_t)b * TT + tb * 64) * KNN;
    for (int l = tid; l < 64 * KNN; l += 256) sidx[l] = ig[l];
    __syncthreads();

    const int tl = tid & 63;
    const int og = tid >> 6;
    const int o0 = og * 16;

    float acc[16];
    #pragma unroll
    for (int q = 0; q < 16; ++q) acc[q] = cb[o0 + q];

    #pragma unroll
    for (int kk = 0; kk < KNN; ++kk) {
        int j = sidx[tl * KNN + kk];
        const unsigned short* up = ub + (((size_t)(b * KNN + kk)) * TT + j) * CH + o0;
        #pragma unroll
        for (int q8 = 0; q8 < 2; ++q8) {
            uint4 raw = *(const uint4*)&up[q8 * 8];
            unsigned rw[4] = {raw.x, raw.y, raw.z, raw.w};
            #pragma unroll
            for (int p = 0; p < 4; ++p) {
                acc[q8 * 8 + 2 * p]     += __uint_as_float(rw[p] << 16);
                acc[q8 * 8 + 2 * p + 1] += __uint_as_float(rw[p] & 0xFFFF0000u);
            }
        }
    }
    const int t = tb * 64 + tl;
    #pragma unroll
    for (int q = 0; q < 16; ++q)
        out[((size_t)b * CH + o0 + q) * TT + t] = acc[q];
}

// ---------------------------------------------------------------------------
extern "C" void kernel_launch(void* const* d_in, const int* in_sizes, int n_in,
                              void* d_out, int out_size, void* d_ws, size_t ws_size,
                              hipStream_t stream) {
    const float* x   = (const float*)d_in[0];
    const float* Wq  = (const float*)d_in[1];
    const float* Wk  = (const float*)d_in[2];
    const float* Wv  = (const float*)d_in[3];
    const float* cw  = (const float*)d_in[4];
    const float* cbp = (const float*)d_in[5];

    float* ws = (float*)d_ws;
    unsigned short* ub  = (unsigned short*)(ws + OFF_UB);
    float* qtf          = ws + OFF_QTF;
    float* ktf          = ws + OFF_KTF;
    unsigned short* qtb = (unsigned short*)(ws + OFF_QTB);
    unsigned short* ktb = (unsigned short*)(ws + OFF_KTB);
    int*   idx          = (int*)(ws + OFF_IDX);
    float* cwp          = ws + OFF_CWP;
    float* out          = (float*)d_out;

    repack_cw_kernel<<<(KNN * CH * CH + 255) / 256, 256, 0, stream>>>(cw, cwp);
    qkvu_kernel<<<BB * 64, 256, 0, stream>>>(x, Wq, Wk, Wv, cwp, qtf, ktf, qtb, ktb, ub);
    sim_topk_kernel<<<BB * 64, 256, 0, stream>>>(qtb, ktb, qtf, ktf, idx);
    gather_conv_kernel<<<BB * 64, 256, 0, stream>>>(ub, idx, cbp, out);
}

// Round 4
// 330.293 us; speedup vs baseline: 1.3193x; 1.0239x over previous
//
#include <hip/hip_runtime.h>
#include <hip/hip_bf16.h>
#include <cstdint>

// Problem constants
#define BB  8
#define CH  64
#define TT  4096
#define KNN 9
#define NEG_INF (-3.402823466e38f)
#define SLOTS 112         // candidate bucket per row (insert2 θ is looser)
#define SSTR  113         // padded LDS stride (odd -> conflict-free scans)
#define KTH   10          // θ = 10th largest of per-strip lane-union (>=9 exact)

typedef short  s16x8 __attribute__((ext_vector_type(8)));   // 8 bf16 MFMA frag
typedef float  f32x4 __attribute__((ext_vector_type(4)));   // MFMA acc

// Workspace layout (float units) — end 16,060,416 floats = 64.2 MB
constexpr size_t OFF_UB  = 0;                                  // u bf16 [B][9][T][C] ushort
constexpr size_t OFF_QTF = (size_t)BB*KNN*TT*CH/2;             //  9,437,184 qhatT f32 [B][T][C]
constexpr size_t OFF_KTF = OFF_QTF + (size_t)BB*TT*CH;         // 11,534,336 khatT f32
constexpr size_t OFF_QTB = OFF_KTF + (size_t)BB*TT*CH;         // 13,631,488 qhatT bf16 ushort
constexpr size_t OFF_KTB = OFF_QTB + (size_t)BB*TT*CH/2;       // 14,680,064 khatT bf16
constexpr size_t OFF_IDX = OFF_KTB + (size_t)BB*TT*CH/2;       // 15,728,640 idx [B][T][9]
constexpr size_t OFF_CWP = OFF_IDX + (size_t)BB*TT*KNN;        // 16,023,552 cwp [9][64][64]

__device__ __forceinline__ unsigned short f2bf(float f) {
    unsigned u = __float_as_uint(f);
    return (unsigned short)((u + 0x7FFFu + ((u >> 16) & 1u)) >> 16);
}

// value-only ascending top-2 (1 med3 + 1 max). s[0]=2nd largest, s[1]=largest.
__device__ __forceinline__ void insert2(float w, float (&s)[2]) {
    s[0] = __builtin_amdgcn_fmed3f(s[0], s[1], w);
    s[1] = fmaxf(s[1], w);
}

// θ = KTH-th largest of the union of the quad's 16 top-2 lists (destroys
// lists). Union ⊆ strip values ⇒ union's KTH-th ≤ strip's KTH-th ≤ strip's
// 9th (KTH=10 ≥ 9). Any strip element in the row-global top-9 is ≥ strip's
// 9th ≥ θ ⇒ collected in pass B. Exact.
__device__ __forceinline__ float popTheta2(float (&s)[2], int lane) {
    float theta = NEG_INF;
    #pragma unroll 1
    for (int p = 0; p < KTH; ++p) {
        float h = s[1];
        float m = h;
        m = fmaxf(m, __shfl_xor(m, 1));
        m = fmaxf(m, __shfl_xor(m, 2));
        m = fmaxf(m, __shfl_xor(m, 4));
        m = fmaxf(m, __shfl_xor(m, 8));
        unsigned long long bal = __ballot(h == m);
        unsigned qb = (unsigned)((bal >> (lane & 48)) & 0xFFFFull);
        int owner = __ffs(qb) - 1;
        if ((lane & 15) == owner) {
            s[1] = s[0]; s[0] = NEG_INF;
        }
        theta = m;
    }
    return theta;
}

// exact sorted-9 insert, value desc w/ index-asc tiebreak (final sort only)
__device__ __forceinline__ void insert9x(float w, int wi, float (&s)[9], int (&si)[9]) {
    bool c[9];
    #pragma unroll
    for (int k = 0; k < 9; ++k) c[k] = (w > s[k]) || (w == s[k] && wi < si[k]);
    #pragma unroll
    for (int k = 0; k < 8; ++k) si[k] = c[k + 1] ? si[k + 1] : (c[k] ? wi : si[k]);
    si[8] = c[8] ? wi : si[8];
    #pragma unroll
    for (int k = 0; k < 8; ++k) s[k] = c[k + 1] ? s[k + 1] : (c[k] ? w : s[k]);
    s[8] = c[8] ? w : s[8];
}

// ---------------------------------------------------------------------------
// K0: repack conv_w[o][cc*9+kk] -> cwp[kk][cc][o]
// ---------------------------------------------------------------------------
__global__ void repack_cw_kernel(const float* __restrict__ cw, float* __restrict__ cwp) {
    int e = blockIdx.x * blockDim.x + threadIdx.x;
    if (e >= KNN * CH * CH) return;
    int o  = e & 63;
    int cc = (e >> 6) & 63;
    int kk = e >> 12;
    cwp[e] = cw[o * (CH * KNN) + cc * KNN + kk];
}

// ---------------------------------------------------------------------------
// K1: QKV + L2 normalize + u-projection (u bf16) + q/k T-layout fp32 & bf16
// ---------------------------------------------------------------------------
__global__ __launch_bounds__(256) void qkvu_kernel(
        const float* __restrict__ x,
        const float* __restrict__ Wq, const float* __restrict__ Wk, const float* __restrict__ Wv,
        const float* __restrict__ cwp,
        float* __restrict__ qtf, float* __restrict__ ktf,
        unsigned short* __restrict__ qtb, unsigned short* __restrict__ ktb,
        unsigned short* __restrict__ ub) {
    __shared__ __align__(16) float xs[CH * 64];
    __shared__ __align__(16) float vs[CH * 64];
    __shared__ __align__(16) float wl[CH * 64];
    __shared__ float pq[4 * 64], pk[4 * 64];

    const int b   = blockIdx.x >> 6;
    const int tb  = blockIdx.x & 63;
    const int tid = threadIdx.x;

    const float* xb = x + ((size_t)b * CH) * TT + tb * 64;
    #pragma unroll
    for (int m = 0; m < 16; ++m) {
        int l = tid + 256 * m;
        xs[l] = xb[(size_t)(l >> 6) * TT + (l & 63)];
    }
    __syncthreads();

    const int t = tid & 63;
    const int g = __builtin_amdgcn_readfirstlane(tid >> 6);
    const int d0 = g * 16;

    float qa[16], ka[16], va[16];
    #pragma unroll
    for (int dd = 0; dd < 16; ++dd) { qa[dd] = 0.f; ka[dd] = 0.f; va[dd] = 0.f; }

    #pragma unroll 4
    for (int c = 0; c < CH; ++c) {
        float xv = xs[c * 64 + t];
        #pragma unroll
        for (int dd = 0; dd < 16; ++dd) {
            qa[dd] = fmaf(Wq[(d0 + dd) * CH + c], xv, qa[dd]);
            ka[dd] = fmaf(Wk[(d0 + dd) * CH + c], xv, ka[dd]);
            va[dd] = fmaf(Wv[(d0 + dd) * CH + c], xv, va[dd]);
        }
    }

    float sq = 0.f, sk = 0.f;
    #pragma unroll
    for (int dd = 0; dd < 16; ++dd) { sq = fmaf(qa[dd], qa[dd], sq); sk = fmaf(ka[dd], ka[dd], sk); }
    pq[g * 64 + t] = sq;
    pk[g * 64 + t] = sk;
    __syncthreads();

    const float nq = sqrtf(pq[t] + pq[64 + t] + pq[128 + t] + pq[192 + t]);
    const float nk = sqrtf(pk[t] + pk[64 + t] + pk[128 + t] + pk[192 + t]);
    const float isq = 1.0f / fmaxf(nq, 1e-12f);
    const float isk = 1.0f / fmaxf(nk, 1e-12f);

    const size_t tg = (size_t)tb * 64 + t;
    float qn[16], kn[16];
    #pragma unroll
    for (int dd = 0; dd < 16; ++dd) {
        qn[dd] = qa[dd] * isq;
        kn[dd] = ka[dd] * isk;
        vs[(d0 + dd) * 64 + t] = va[dd];
    }
    float* qf = qtf + ((size_t)b * TT + tg) * CH + d0;
    float* kf = ktf + ((size_t)b * TT + tg) * CH + d0;
    #pragma unroll
    for (int p = 0; p < 4; ++p) {
        *(float4*)&qf[p * 4] = make_float4(qn[p*4], qn[p*4+1], qn[p*4+2], qn[p*4+3]);
        *(float4*)&kf[p * 4] = make_float4(kn[p*4], kn[p*4+1], kn[p*4+2], kn[p*4+3]);
    }
    unsigned* qh = (unsigned*)(qtb + ((size_t)b * TT + tg) * CH + d0);
    unsigned* kh = (unsigned*)(ktb + ((size_t)b * TT + tg) * CH + d0);
    #pragma unroll
    for (int p = 0; p < 8; ++p) {
        qh[p] = (unsigned)f2bf(qn[2*p]) | ((unsigned)f2bf(qn[2*p+1]) << 16);
        kh[p] = (unsigned)f2bf(kn[2*p]) | ((unsigned)f2bf(kn[2*p+1]) << 16);
    }
    __syncthreads();

    const int to = tid & 15;
    const int tt = tid >> 4;
    for (int kk = 0; kk < KNN; ++kk) {
        #pragma unroll
        for (int m = 0; m < 16; ++m) {
            int l = tid + 256 * m;
            wl[l] = cwp[kk * (CH * CH) + l];
        }
        __syncthreads();
        float acc[4][4];
        #pragma unroll
        for (int i = 0; i < 4; ++i)
            #pragma unroll
            for (int j = 0; j < 4; ++j) acc[i][j] = 0.f;

        #pragma unroll 8
        for (int cc = 0; cc < CH; ++cc) {
            float4 wv = *(const float4*)&wl[cc * 64 + 4 * to];
            float4 vv = *(const float4*)&vs[cc * 64 + 4 * tt];
            const float wj[4] = {wv.x, wv.y, wv.z, wv.w};
            const float vi[4] = {vv.x, vv.y, vv.z, vv.w};
            #pragma unroll
            for (int i = 0; i < 4; ++i)
                #pragma unroll
                for (int j = 0; j < 4; ++j) acc[i][j] = fmaf(vi[i], wj[j], acc[i][j]);
        }
        #pragma unroll
        for (int i = 0; i < 4; ++i) {
            size_t row = (size_t)(b * KNN + kk) * TT + tb * 64 + 4 * tt + i;
            unsigned w0 = (unsigned)f2bf(acc[i][0]) | ((unsigned)f2bf(acc[i][1]) << 16);
            unsigned w1 = (unsigned)f2bf(acc[i][2]) | ((unsigned)f2bf(acc[i][3]) << 16);
            *(uint2*)&ub[row * CH + 4 * to] = make_uint2(w0, w1);
        }
        __syncthreads();
    }
}

// ---------------------------------------------------------------------------
// K2: BARRIER-FREE bf16-MFMA sim + top-2 prefilter + θ-collect + exact rescore
//     grid 512 = b(8, XCD: batch's q/k L2-resident) x ib(64).
//     Block: 64 k-rows x 4096 q-cols. 4 waves; wave w owns ALL 64 rows
//     (ka[4][2] in regs) x a 1024-col strip. This round:
//     (1) insert2 prefilter (2 VALU/elem, was 4) — exact via subset order
//         statistics; s-lists shrink 64->32 VGPR.
//     (2) 2-stage qA/qB load pipeline (affordable now): next tile's loads
//         issue before current tile's insert VALU -> L2 latency hidden.
//     SLOTS 112 (looser θ -> more candidates), stride 113 odd.
// ---------------------------------------------------------------------------
__global__ __launch_bounds__(256, 2) void sim_topk_kernel(
        const unsigned short* __restrict__ qtb, const unsigned short* __restrict__ ktb,
        const float* __restrict__ qtf, const float* __restrict__ ktf,
        int* __restrict__ idxout) {
    __shared__ int   cnt[64];
    __shared__ int   bkt[64 * SSTR];
    __shared__ float wbf[64 * SSTR];

    const int b    = blockIdx.x & 7;
    const int ib   = blockIdx.x >> 3;      // 0..63
    const int tid  = threadIdx.x;
    const int lane = tid & 63;
    const int w    = __builtin_amdgcn_readfirstlane(tid >> 6);  // wave -> col strip
    const int quad = lane >> 4;
    const int l15  = lane & 15;

    if (tid < 64) cnt[tid] = 0;
    __syncthreads();

    // k A-fragments: ALL 64 rows. row = rt*16 + l15, k-chunk = quad*8 + ks*32
    const unsigned short* kb = ktb + ((size_t)b * TT + ib * 64) * CH;
    s16x8 ka[4][2];
    #pragma unroll
    for (int rt = 0; rt < 4; ++rt)
        #pragma unroll
        for (int ks = 0; ks < 2; ++ks)
            ka[rt][ks] = *(const s16x8*)(kb + (size_t)(rt * 16 + l15) * CH + ks * 32 + quad * 8);

    const unsigned short* qbB = qtb + ((size_t)b * TT + w * 1024) * CH;

    // per-(rt,rg) ascending top-2 lists over this wave's strip
    float s[4][4][2];
    #pragma unroll
    for (int rt = 0; rt < 4; ++rt)
        #pragma unroll
        for (int rg = 0; rg < 4; ++rg) { s[rt][rg][0] = NEG_INF; s[rt][rg][1] = NEG_INF; }

    // load one 64-col step of q B-frags: col j = it*64 + jj*16 + l15
    auto LOADQ = [&](s16x8 (&qf)[4][2], int it) {
        const unsigned short* qrow = qbB + (size_t)(it * 64 + l15) * CH + quad * 8;
        #pragma unroll
        for (int jj = 0; jj < 4; ++jj)
            #pragma unroll
            for (int ks = 0; ks < 2; ++ks)
                qf[jj][ks] = *(const s16x8*)(qrow + (size_t)jj * 16 * CH + ks * 32);
    };

    // ------------------ PASS A: values-only top-2 (no barriers) ------------
    auto COMPA = [&](const s16x8 (&qf)[4][2]) {
        #pragma unroll
        for (int rt = 0; rt < 4; ++rt) {
            f32x4 acc[4];
            #pragma unroll
            for (int jj = 0; jj < 4; ++jj) acc[jj] = (f32x4){0.f, 0.f, 0.f, 0.f};
            #pragma unroll
            for (int ks = 0; ks < 2; ++ks)
                #pragma unroll
                for (int jj = 0; jj < 4; ++jj)
                    acc[jj] = __builtin_amdgcn_mfma_f32_16x16x32_bf16(ka[rt][ks], qf[jj][ks], acc[jj], 0, 0, 0);
            #pragma unroll
            for (int jj = 0; jj < 4; ++jj) {
                insert2(acc[jj][0], s[rt][0]);
                insert2(acc[jj][1], s[rt][1]);
                insert2(acc[jj][2], s[rt][2]);
                insert2(acc[jj][3], s[rt][3]);
            }
        }
    };

    {
        s16x8 qA[4][2], qB[4][2];
        LOADQ(qA, 0);
        #pragma unroll 1
        for (int it = 0; it < 14; it += 2) {
            LOADQ(qB, it + 1);     // in flight during COMPA(qA)'s MFMA+insert
            COMPA(qA);
            LOADQ(qA, it + 2);     // in flight during COMPA(qB)
            COMPA(qB);
        }
        LOADQ(qB, 15);
        COMPA(qA);
        COMPA(qB);
    }

    // per-(row, strip) θ — valid per strip; no cross-wave merge needed
    float th[4][4];
    #pragma unroll
    for (int rt = 0; rt < 4; ++rt)
        #pragma unroll
        for (int rg = 0; rg < 4; ++rg)
            th[rt][rg] = popTheta2(s[rt][rg], lane);

    // ------------------ PASS B: recompute (bitwise-identical) + collect ----
    auto COMPB = [&](const s16x8 (&qf)[4][2], int it) {
        #pragma unroll
        for (int rt = 0; rt < 4; ++rt) {
            f32x4 acc[4];
            #pragma unroll
            for (int jj = 0; jj < 4; ++jj) acc[jj] = (f32x4){0.f, 0.f, 0.f, 0.f};
            #pragma unroll
            for (int ks = 0; ks < 2; ++ks)
                #pragma unroll
                for (int jj = 0; jj < 4; ++jj)
                    acc[jj] = __builtin_amdgcn_mfma_f32_16x16x32_bf16(ka[rt][ks], qf[jj][ks], acc[jj], 0, 0, 0);
            #pragma unroll
            for (int jj = 0; jj < 4; ++jj) {
                const int j = w * 1024 + it * 64 + jj * 16 + l15;
                #pragma unroll
                for (int rg = 0; rg < 4; ++rg) {
                    if (acc[jj][rg] >= th[rt][rg]) {
                        int rowl = rt * 16 + quad * 4 + rg;     // 0..63
                        int sl = atomicAdd(&cnt[rowl], 1);
                        if (sl < SLOTS) bkt[rowl * SSTR + sl] = j;
                    }
                }
            }
        }
    };

    {
        s16x8 qA[4][2], qB[4][2];
        LOADQ(qA, 0);
        #pragma unroll 1
        for (int it = 0; it < 14; it += 2) {
            LOADQ(qB, it + 1);
            COMPB(qA, it);
            LOADQ(qA, it + 2);
            COMPB(qB, it + 1);
        }
        LOADQ(qB, 15);
        COMPB(qA, 14);
        COMPB(qB, 15);
    }
    __syncthreads();

    // ------------------ exact fp32 rescore (L2-hot q/k fp32) ---------------
    {
        int r = tid >> 2, sub = tid & 3;
        int n = min(cnt[r], SLOTS);
        const float* krow = ktf + ((size_t)b * TT + ib * 64 + r) * CH;
        for (int m = sub; m < n; m += 4) {
            int j = bkt[r * SSTR + m];
            const float* qrow = qtf + ((size_t)b * TT + j) * CH;
            float wv = 0.f;
            #pragma unroll
            for (int c4 = 0; c4 < 16; ++c4) {
                float4 kv = *(const float4*)&krow[c4 * 4];
                float4 qv = *(const float4*)&qrow[c4 * 4];
                wv = fmaf(kv.x, qv.x, wv); wv = fmaf(kv.y, qv.y, wv);
                wv = fmaf(kv.z, qv.z, wv); wv = fmaf(kv.w, qv.w, wv);
            }
            wbf[r * SSTR + m] = wv;
        }
    }
    __syncthreads();

    if (tid < 64) {
        int n = min(cnt[tid], SLOTS);
        float s9[9]; int si9[9];
        #pragma unroll
        for (int k = 0; k < 9; ++k) { s9[k] = NEG_INF; si9[k] = 0x7fffffff; }
        #pragma unroll 1
        for (int m = 0; m < n; ++m) insert9x(wbf[tid * SSTR + m], bkt[tid * SSTR + m], s9, si9);
        int* orow = idxout + ((size_t)b * TT + ib * 64 + tid) * KNN;
        #pragma unroll
        for (int m = 0; m < 9; ++m) orow[m] = si9[8 - m];
    }
}

// ---------------------------------------------------------------------------
// K3: out[b][o][t] = conv_b[o] + sum_kk u_bf16[b][kk][idx[t][kk]][o]
// ---------------------------------------------------------------------------
__global__ __launch_bounds__(256) void gather_conv_kernel(
        const unsigned short* __restrict__ ub, const int* __restrict__ idxin,
        const float* __restrict__ conv_b, float* __restrict__ out) {
    __shared__ int   sidx[64 * KNN];
    __shared__ float cb[CH];
    const int b   = blockIdx.x & 7;
    const int tb  = blockIdx.x >> 3;
    const int tid = threadIdx.x;

    if (tid < CH) cb[tid] = conv_b[tid];
    const int* ig = idxin + ((size_t)b * TT + tb * 64) * KNN;
    for (int l = tid; l < 64 * KNN; l += 256) sidx[l] = ig[l];
    __syncthreads();

    const int tl = tid & 63;
    const int og = tid >> 6;
    const int o0 = og * 16;

    float acc[16];
    #pragma unroll
    for (int q = 0; q < 16; ++q) acc[q] = cb[o0 + q];

    #pragma unroll
    for (int kk = 0; kk < KNN; ++kk) {
        int j = sidx[tl * KNN + kk];
        const unsigned short* up = ub + (((size_t)(b * KNN + kk)) * TT + j) * CH + o0;
        #pragma unroll
        for (int q8 = 0; q8 < 2; ++q8) {
            uint4 raw = *(const uint4*)&up[q8 * 8];
            unsigned rw[4] = {raw.x, raw.y, raw.z, raw.w};
            #pragma unroll
            for (int p = 0; p < 4; ++p) {
                acc[q8 * 8 + 2 * p]     += __uint_as_float(rw[p] << 16);
                acc[q8 * 8 + 2 * p + 1] += __uint_as_float(rw[p] & 0xFFFF0000u);
            }
        }
    }
    const int t = tb * 64 + tl;
    #pragma unroll
    for (int q = 0; q < 16; ++q)
        out[((size_t)b * CH + o0 + q) * TT + t] = acc[q];
}

// ---------------------------------------------------------------------------
extern "C" void kernel_launch(void* const* d_in, const int* in_sizes, int n_in,
                              void* d_out, int out_size, void* d_ws, size_t ws_size,
                              hipStream_t stream) {
    const float* x   = (const float*)d_in[0];
    const float* Wq  = (const float*)d_in[1];
    const float* Wk  = (const float*)d_in[2];
    const float* Wv  = (const float*)d_in[3];
    const float* cw  = (const float*)d_in[4];
    const float* cbp = (const float*)d_in[5];

    float* ws = (float*)d_ws;
    unsigned short* ub  = (unsigned short*)(ws + OFF_UB);
    float* qtf          = ws + OFF_QTF;
    float* ktf          = ws + OFF_KTF;
    unsigned short* qtb = (unsigned short*)(ws + OFF_QTB);
    unsigned short* ktb = (unsigned short*)(ws + OFF_KTB);
    int*   idx          = (int*)(ws + OFF_IDX);
    float* cwp          = ws + OFF_CWP;
    float* out          = (float*)d_out;

    repack_cw_kernel<<<(KNN * CH * CH + 255) / 256, 256, 0, stream>>>(cw, cwp);
    qkvu_kernel<<<BB * 64, 256, 0, stream>>>(x, Wq, Wk, Wv, cwp, qtf, ktf, qtb, ktb, ub);
    sim_topk_kernel<<<BB * 64, 256, 0, stream>>>(qtb, ktb, qtf, ktf, idx);
    gather_conv_kernel<<<BB * 64, 256, 0, stream>>>(ub, idx, cbp, out);
}